// Round 7
// baseline (467.636 us; speedup 1.0000x reference)
//
#include <hip/hip_runtime.h>
#include <math.h>

// Problem constants (fixed by the reference setup)
#define NPTS 262144
#define DIM 256
#define NB 16

#define BLOCKS 2048
#define THREADS 256
#define ROWS_PER_BLOCK (NPTS / BLOCKS)        // 128 contiguous rows per block
#define WAVES_PER_BLOCK (THREADS / 64)        // 4
#define ITERS (ROWS_PER_BLOCK / WAVES_PER_BLOCK)  // 32 rows per wave

// Kernel 1: segment-sum of score-weighted features + segment counts.
// Wave w of a block handles rows  base + w + 4*it  (one full 1KB row per wave
// per iteration: 64 lanes x float4). seg is sorted, so per-thread register
// accumulation with flush-on-batch-change keeps atomics rare and wave-uniform.
__global__ __launch_bounds__(THREADS) void seg_reduce_kernel(
    const float* __restrict__ pf,
    const float* __restrict__ scores,
    const int*   __restrict__ coords,
    float* __restrict__ sums,    // [NB][DIM]
    float* __restrict__ counts)  // [NB]
{
    const int t    = threadIdx.x;
    const int lane = t & 63;
    const int wid  = t >> 6;                    // 0..3
    const int col4 = lane << 2;                 // column start: 0,4,...,252
    const int base_row = blockIdx.x * ROWS_PER_BLOCK + wid;

    float acc0 = 0.f, acc1 = 0.f, acc2 = 0.f, acc3 = 0.f;
    float cnt = 0.f;
    int cur_b = -1;

    for (int it = 0; it < ITERS; ++it) {
        const int row = base_row + it * WAVES_PER_BLOCK;
        const int b   = coords[(size_t)row * 4];     // wave-uniform broadcast
        const float s = scores[row];                 // wave-uniform broadcast

        if (b != cur_b) {                            // wave-uniform branch (sorted seg)
            if (cur_b >= 0) {
                float* dst = sums + (size_t)cur_b * DIM + col4;
                atomicAdd(dst + 0, acc0);
                atomicAdd(dst + 1, acc1);
                atomicAdd(dst + 2, acc2);
                atomicAdd(dst + 3, acc3);
                if (lane == 0) atomicAdd(counts + cur_b, cnt);
            }
            acc0 = acc1 = acc2 = acc3 = 0.f;
            cnt = 0.f;
            cur_b = b;
        }

        const float4 f = *reinterpret_cast<const float4*>(pf + (size_t)row * DIM + col4);
        acc0 = fmaf(s, f.x, acc0);
        acc1 = fmaf(s, f.y, acc1);
        acc2 = fmaf(s, f.z, acc2);
        acc3 = fmaf(s, f.w, acc3);
        cnt += 1.f;
    }

    if (cur_b >= 0) {
        float* dst = sums + (size_t)cur_b * DIM + col4;
        atomicAdd(dst + 0, acc0);
        atomicAdd(dst + 1, acc1);
        atomicAdd(dst + 2, acc2);
        atomicAdd(dst + 3, acc3);
        if (lane == 0) atomicAdd(counts + cur_b, cnt);
    }
}

// Kernel 2: scene = sums/counts ; out = sigmoid(scene . w + bias).
// 16 waves, one per batch; 64-lane shuffle reduction, no LDS.
__global__ __launch_bounds__(1024) void head_kernel(
    const float* __restrict__ sums,
    const float* __restrict__ counts,
    const float* __restrict__ w,
    const float* __restrict__ bias,
    float* __restrict__ out)
{
    const int t    = threadIdx.x;
    const int b    = t >> 6;        // wave id == batch id (16 waves)
    const int lane = t & 63;
    const int c    = lane << 2;

    const float inv = 1.f / counts[b];
    const float4 sv = *reinterpret_cast<const float4*>(sums + (size_t)b * DIM + c);
    const float4 wv = *reinterpret_cast<const float4*>(w + c);
    float p = (sv.x * wv.x + sv.y * wv.y + sv.z * wv.z + sv.w * wv.w) * inv;

    #pragma unroll
    for (int off = 32; off > 0; off >>= 1)
        p += __shfl_down(p, off, 64);

    if (lane == 0)
        out[b] = 1.f / (1.f + expf(-(p + bias[0])));
}

extern "C" void kernel_launch(void* const* d_in, const int* in_sizes, int n_in,
                              void* d_out, int out_size, void* d_ws, size_t ws_size,
                              hipStream_t stream) {
    const float* pf      = (const float*)d_in[0];   // [N][D] f32
    const float* scores  = (const float*)d_in[1];   // [N] f32
    const int*   coords  = (const int*)d_in[2];     // [N][4] i32 (col 0 = sorted batch idx)
    const float* fc_w    = (const float*)d_in[3];   // [1][D] f32
    const float* fc_b    = (const float*)d_in[4];   // [1] f32
    (void)in_sizes; (void)n_in; (void)out_size; (void)ws_size;

    float* sums   = (float*)d_ws;                   // [NB][DIM]
    float* counts = sums + (size_t)NB * DIM;        // [NB]
    float* out    = (float*)d_out;                  // [NB][1] f32

    // d_ws is re-poisoned to 0xAA before every launch: zero the accumulators.
    hipMemsetAsync(d_ws, 0, (size_t)(NB * DIM + NB) * sizeof(float), stream);

    seg_reduce_kernel<<<BLOCKS, THREADS, 0, stream>>>(pf, scores, coords, sums, counts);
    head_kernel<<<1, 1024, 0, stream>>>(sums, counts, fc_w, fc_b, out);
}

// Round 9
// 373.829 us; speedup vs baseline: 1.2509x; 1.2509x over previous
//
#include <hip/hip_runtime.h>
#include <math.h>

// Problem constants (fixed by the reference setup)
#define NPTS 262144
#define DIM 256
#define NB 16

#define BLOCKS 2048
#define THREADS 256
#define RPB 128                       // contiguous rows per block
#define WAVES 4                       // waves per block
#define ITERS (RPB / WAVES)           // 32 rows per wave

// Kernel 1: segment-sum of score-weighted features + segment counts.
// Metadata (batch id, score) for the block's 128 rows is staged in LDS up
// front, so the streaming loop has NO dependent global loads — round 7
// showed the coords-load -> branch -> feature-load chain made the kernel
// latency-bound (203us, 2% VALUBusy, 10% HBM). seg is sorted, so almost
// every block lies in one segment: branch-free unrolled fast path with 8
// float4 loads in flight per wave, LDS cross-wave reduce, one atomic set
// per block (4x fewer atomics; WRITE_SIZE was 33MB of atomic RMW traffic).
__global__ __launch_bounds__(THREADS) void seg_reduce_kernel(
    const float* __restrict__ pf,
    const float* __restrict__ scores,
    const int*   __restrict__ coords,
    float* __restrict__ sums,    // [NB][DIM]
    float* __restrict__ counts)  // [NB]
{
    __shared__ float s_score[RPB];
    __shared__ int   s_batch[RPB];
    __shared__ float s_part[WAVES][DIM];   // 4 KB, fast-path reduce

    const int t    = threadIdx.x;
    const int lane = t & 63;
    const int wid  = t >> 6;              // 0..3
    const int col4 = lane << 2;           // 0,4,...,252
    const int row0 = blockIdx.x * RPB;

    // One-time metadata stage (coords stride 4: col 0 is the sorted batch idx)
    if (t < RPB) {
        s_score[t] = scores[row0 + t];
        s_batch[t] = coords[(size_t)(row0 + t) * 4];
    }
    __syncthreads();

    const float* base = pf + (size_t)row0 * DIM + col4;

    if (s_batch[0] == s_batch[RPB - 1]) {
        // ---- fast path: whole block in one segment (sorted => all equal) ----
        float a0 = 0.f, a1 = 0.f, a2 = 0.f, a3 = 0.f;
        #pragma unroll 8
        for (int it = 0; it < ITERS; ++it) {
            const int r   = (it << 2) + wid;        // 4 waves cover 4 consecutive rows
            const float s = s_score[r];
            const float4 f = *reinterpret_cast<const float4*>(base + (size_t)r * DIM);
            a0 = fmaf(s, f.x, a0);
            a1 = fmaf(s, f.y, a1);
            a2 = fmaf(s, f.z, a2);
            a3 = fmaf(s, f.w, a3);
        }
        // cross-wave reduce in LDS, then ONE atomic set per block
        float4* dstp = reinterpret_cast<float4*>(&s_part[wid][col4]);
        *dstp = make_float4(a0, a1, a2, a3);
        __syncthreads();
        const int b0 = s_batch[0];
        const float v = s_part[0][t] + s_part[1][t] + s_part[2][t] + s_part[3][t];
        atomicAdd(&sums[(size_t)b0 * DIM + t], v);
        if (t == 0) atomicAdd(&counts[b0], (float)RPB);
    } else {
        // ---- slow path: block spans a segment boundary (<= 15 of 2048) ----
        float a0 = 0.f, a1 = 0.f, a2 = 0.f, a3 = 0.f;
        float cnt = 0.f;
        int cur_b = -1;
        for (int it = 0; it < ITERS; ++it) {
            const int r   = (it << 2) + wid;
            const int b   = s_batch[r];
            const float s = s_score[r];
            if (b != cur_b) {                       // wave-uniform (sorted)
                if (cur_b >= 0) {
                    float* dst = sums + (size_t)cur_b * DIM + col4;
                    atomicAdd(dst + 0, a0);
                    atomicAdd(dst + 1, a1);
                    atomicAdd(dst + 2, a2);
                    atomicAdd(dst + 3, a3);
                    if (lane == 0) atomicAdd(counts + cur_b, cnt);
                }
                a0 = a1 = a2 = a3 = 0.f;
                cnt = 0.f;
                cur_b = b;
            }
            const float4 f = *reinterpret_cast<const float4*>(base + (size_t)r * DIM);
            a0 = fmaf(s, f.x, a0);
            a1 = fmaf(s, f.y, a1);
            a2 = fmaf(s, f.z, a2);
            a3 = fmaf(s, f.w, a3);
            cnt += 1.f;
        }
        if (cur_b >= 0) {
            float* dst = sums + (size_t)cur_b * DIM + col4;
            atomicAdd(dst + 0, a0);
            atomicAdd(dst + 1, a1);
            atomicAdd(dst + 2, a2);
            atomicAdd(dst + 3, a3);
            if (lane == 0) atomicAdd(counts + cur_b, cnt);
        }
    }
}

// Kernel 2: scene = sums/counts ; out = sigmoid(scene . w + bias).
// 16 waves, one per batch; 64-lane shuffle reduction, no LDS.
__global__ __launch_bounds__(1024) void head_kernel(
    const float* __restrict__ sums,
    const float* __restrict__ counts,
    const float* __restrict__ w,
    const float* __restrict__ bias,
    float* __restrict__ out)
{
    const int t    = threadIdx.x;
    const int b    = t >> 6;        // wave id == batch id (16 waves)
    const int lane = t & 63;
    const int c    = lane << 2;

    const float inv = 1.f / counts[b];
    const float4 sv = *reinterpret_cast<const float4*>(sums + (size_t)b * DIM + c);
    const float4 wv = *reinterpret_cast<const float4*>(w + c);
    float p = (sv.x * wv.x + sv.y * wv.y + sv.z * wv.z + sv.w * wv.w) * inv;

    #pragma unroll
    for (int off = 32; off > 0; off >>= 1)
        p += __shfl_down(p, off, 64);

    if (lane == 0)
        out[b] = 1.f / (1.f + expf(-(p + bias[0])));
}

extern "C" void kernel_launch(void* const* d_in, const int* in_sizes, int n_in,
                              void* d_out, int out_size, void* d_ws, size_t ws_size,
                              hipStream_t stream) {
    const float* pf      = (const float*)d_in[0];   // [N][D] f32
    const float* scores  = (const float*)d_in[1];   // [N] f32
    const int*   coords  = (const int*)d_in[2];     // [N][4] i32 (col 0 = sorted batch idx)
    const float* fc_w    = (const float*)d_in[3];   // [1][D] f32
    const float* fc_b    = (const float*)d_in[4];   // [1] f32
    (void)in_sizes; (void)n_in; (void)out_size; (void)ws_size;

    float* sums   = (float*)d_ws;                   // [NB][DIM]
    float* counts = sums + (size_t)NB * DIM;        // [NB]
    float* out    = (float*)d_out;                  // [NB][1] f32

    // d_ws is re-poisoned to 0xAA before every launch: zero the accumulators.
    hipMemsetAsync(d_ws, 0, (size_t)(NB * DIM + NB) * sizeof(float), stream);

    seg_reduce_kernel<<<BLOCKS, THREADS, 0, stream>>>(pf, scores, coords, sums, counts);
    head_kernel<<<1, 1024, 0, stream>>>(sums, counts, fc_w, fc_b, out);
}

// Round 11
// 369.643 us; speedup vs baseline: 1.2651x; 1.0113x over previous
//
#include <hip/hip_runtime.h>
#include <math.h>

// Problem constants (fixed by the reference setup)
#define NPTS 262144
#define DIM 256
#define NB 16

#define BLOCKS 4096
#define THREADS 256
#define RPB 64                        // contiguous rows per block
#define WAVES 4                       // waves per block
#define ITERS (RPB / WAVES)           // 16 rows per wave

// Kernel 1: segment-sum of score-weighted features + segment counts.
// R7: latency-bound (203us, VALUBusy 2%, HBM 10%) from coords->branch->load
// dependent chain. R9: LDS-staged metadata + branch-free fast path -> ~110us
// (inferred: dur 467->374, harness poison/restore ~235us is immovable).
// This round: 4096 blocks x 64 rows, FULLY unrolled fast loop (16 independent
// dwordx4 loads = 16KB in flight per wave, no drain bubble) + smoother ramp.
__global__ __launch_bounds__(THREADS) void seg_reduce_kernel(
    const float* __restrict__ pf,
    const float* __restrict__ scores,
    const int*   __restrict__ coords,
    float* __restrict__ sums,    // [NB][DIM]
    float* __restrict__ counts)  // [NB]
{
    __shared__ float s_score[RPB];
    __shared__ int   s_batch[RPB];
    __shared__ float s_part[WAVES][DIM];   // 4 KB, fast-path reduce

    const int t    = threadIdx.x;
    const int lane = t & 63;
    const int wid  = t >> 6;              // 0..3
    const int col4 = lane << 2;           // 0,4,...,252
    const int row0 = blockIdx.x * RPB;

    // One-time metadata stage (coords stride 4: col 0 is the sorted batch idx)
    if (t < RPB) {
        s_score[t] = scores[row0 + t];
        s_batch[t] = coords[(size_t)(row0 + t) * 4];
    }
    __syncthreads();

    const float* base = pf + (size_t)row0 * DIM + col4;

    if (s_batch[0] == s_batch[RPB - 1]) {
        // ---- fast path: whole block in one segment (sorted => all equal) ----
        float a0 = 0.f, a1 = 0.f, a2 = 0.f, a3 = 0.f;
        #pragma unroll
        for (int it = 0; it < ITERS; ++it) {
            const int r   = (it << 2) + wid;        // 4 waves cover 4 consecutive rows
            const float s = s_score[r];
            const float4 f = *reinterpret_cast<const float4*>(base + (size_t)r * DIM);
            a0 = fmaf(s, f.x, a0);
            a1 = fmaf(s, f.y, a1);
            a2 = fmaf(s, f.z, a2);
            a3 = fmaf(s, f.w, a3);
        }
        // cross-wave reduce in LDS, then ONE atomic set per block
        float4* dstp = reinterpret_cast<float4*>(&s_part[wid][col4]);
        *dstp = make_float4(a0, a1, a2, a3);
        __syncthreads();
        const int b0 = s_batch[0];
        const float v = s_part[0][t] + s_part[1][t] + s_part[2][t] + s_part[3][t];
        atomicAdd(&sums[(size_t)b0 * DIM + t], v);
        if (t == 0) atomicAdd(&counts[b0], (float)RPB);
    } else {
        // ---- slow path: block spans a segment boundary (<= 15 of 4096) ----
        float a0 = 0.f, a1 = 0.f, a2 = 0.f, a3 = 0.f;
        float cnt = 0.f;
        int cur_b = -1;
        for (int it = 0; it < ITERS; ++it) {
            const int r   = (it << 2) + wid;
            const int b   = s_batch[r];
            const float s = s_score[r];
            if (b != cur_b) {                       // wave-uniform (sorted)
                if (cur_b >= 0) {
                    float* dst = sums + (size_t)cur_b * DIM + col4;
                    atomicAdd(dst + 0, a0);
                    atomicAdd(dst + 1, a1);
                    atomicAdd(dst + 2, a2);
                    atomicAdd(dst + 3, a3);
                    if (lane == 0) atomicAdd(counts + cur_b, cnt);
                }
                a0 = a1 = a2 = a3 = 0.f;
                cnt = 0.f;
                cur_b = b;
            }
            const float4 f = *reinterpret_cast<const float4*>(base + (size_t)r * DIM);
            a0 = fmaf(s, f.x, a0);
            a1 = fmaf(s, f.y, a1);
            a2 = fmaf(s, f.z, a2);
            a3 = fmaf(s, f.w, a3);
            cnt += 1.f;
        }
        if (cur_b >= 0) {
            float* dst = sums + (size_t)cur_b * DIM + col4;
            atomicAdd(dst + 0, a0);
            atomicAdd(dst + 1, a1);
            atomicAdd(dst + 2, a2);
            atomicAdd(dst + 3, a3);
            if (lane == 0) atomicAdd(counts + cur_b, cnt);
        }
    }
}

// Kernel 2: scene = sums/counts ; out = sigmoid(scene . w + bias).
// 16 waves, one per batch; 64-lane shuffle reduction, no LDS.
__global__ __launch_bounds__(1024) void head_kernel(
    const float* __restrict__ sums,
    const float* __restrict__ counts,
    const float* __restrict__ w,
    const float* __restrict__ bias,
    float* __restrict__ out)
{
    const int t    = threadIdx.x;
    const int b    = t >> 6;        // wave id == batch id (16 waves)
    const int lane = t & 63;
    const int c    = lane << 2;

    const float inv = 1.f / counts[b];
    const float4 sv = *reinterpret_cast<const float4*>(sums + (size_t)b * DIM + c);
    const float4 wv = *reinterpret_cast<const float4*>(w + c);
    float p = (sv.x * wv.x + sv.y * wv.y + sv.z * wv.z + sv.w * wv.w) * inv;

    #pragma unroll
    for (int off = 32; off > 0; off >>= 1)
        p += __shfl_down(p, off, 64);

    if (lane == 0)
        out[b] = 1.f / (1.f + expf(-(p + bias[0])));
}

extern "C" void kernel_launch(void* const* d_in, const int* in_sizes, int n_in,
                              void* d_out, int out_size, void* d_ws, size_t ws_size,
                              hipStream_t stream) {
    const float* pf      = (const float*)d_in[0];   // [N][D] f32
    const float* scores  = (const float*)d_in[1];   // [N] f32
    const int*   coords  = (const int*)d_in[2];     // [N][4] i32 (col 0 = sorted batch idx)
    const float* fc_w    = (const float*)d_in[3];   // [1][D] f32
    const float* fc_b    = (const float*)d_in[4];   // [1] f32
    (void)in_sizes; (void)n_in; (void)out_size; (void)ws_size;

    float* sums   = (float*)d_ws;                   // [NB][DIM]
    float* counts = sums + (size_t)NB * DIM;        // [NB]
    float* out    = (float*)d_out;                  // [NB][1] f32

    // d_ws is re-poisoned to 0xAA before every launch: zero the accumulators.
    hipMemsetAsync(d_ws, 0, (size_t)(NB * DIM + NB) * sizeof(float), stream);

    seg_reduce_kernel<<<BLOCKS, THREADS, 0, stream>>>(pf, scores, coords, sums, counts);
    head_kernel<<<1, 1024, 0, stream>>>(sums, counts, fc_w, fc_b, out);
}